// Round 4
// baseline (546.098 us; speedup 1.0000x reference)
//
#include <hip/hip_runtime.h>

// Problem constants (fixed by setup_inputs) — all tensors fp32 on the wire.
#define C_CH  512
#define R_CH  128
#define BATCH 8
#define HW    16384                 // 128*128
#define HW4   (HW / 4)              // 4096 float4 per plane
#define NPLANE (BATCH * C_CH)       // 4096
#define TPB   256
#define PPB   2                     // planes per add-block (same batch)
#define CHUNK_PLANES 1024           // 2 batches = 67 MB, fits L3 with margin
#define MEAN_BLOCKS  CHUNK_PLANES   // 1024
#define ADD_BLOCKS   (CHUNK_PLANES / PPB)  // 512

// Native vector type — nontemporal builtins reject HIP_vector_type.
typedef float floatx4 __attribute__((ext_vector_type(4)));

__device__ __forceinline__ float relu6f(float v) {
    return fminf(fmaxf(v, 0.0f), 6.0f);
}

// ---- mean over one plane; normal (caching) loads POPULATE L3 for the add
// pass of the same chunk two launches later. ----
__global__ __launch_bounds__(TPB) void mean_kernel(const float4* __restrict__ x,
                                                   float* __restrict__ meanv,
                                                   int plane_base) {
    const int plane = plane_base + blockIdx.x;
    const float4* px = x + (size_t)plane * HW4;
    float s = 0.0f;
#pragma unroll
    for (int it = 0; it < HW4 / TPB; ++it) {
        float4 v = px[threadIdx.x + it * TPB];
        s += (v.x + v.y) + (v.z + v.w);
    }
    __shared__ float red[TPB];
    red[threadIdx.x] = s;
    __syncthreads();
    for (int off = TPB / 2; off > 0; off >>= 1) {
        if (threadIdx.x < off) red[threadIdx.x] += red[threadIdx.x + off];
        __syncthreads();
    }
    if (threadIdx.x == 0) meanv[plane] = red[0] * (1.0f / (float)HW);
}

// ---- fused MLP + BN + residual add for PPB planes of one batch. x read with
// nt loads (L3 hits from the chunk's mean pass, no re-promote), out written
// with nt stores (write stream never allocates in L2/L3). ----
__global__ __launch_bounds__(TPB) void add_kernel(
    const floatx4* __restrict__ x,
    const float* __restrict__ meanv,
    const float* __restrict__ wg,      // [R_CH, C_CH]
    const float* __restrict__ wf,      // [C_CH, R_CH]
    const float* __restrict__ gamma,
    const float* __restrict__ beta,
    const float* __restrict__ mu,
    const float* __restrict__ var,
    floatx4* __restrict__ out,
    int plane_base) {
    const int plane0 = plane_base + (int)blockIdx.x * PPB;
    const int b  = plane0 >> 9;                   // /C_CH
    const int c0 = plane0 & (C_CH - 1);
    const int tid = threadIdx.x;

    __shared__ float m[C_CH];
    __shared__ float part[TPB];
    __shared__ float t[R_CH];
    __shared__ float ys[PPB];

    for (int c = tid; c < C_CH; c += TPB) m[c] = meanv[b * C_CH + c];
    __syncthreads();

    // t[r] = relu6(dot(wg[r,:], m)) — 2 threads per row, half row each.
    {
        const int r = tid & (R_CH - 1);
        const int half = tid >> 7;                // 0 or 1
        const float4* w4 = (const float4*)(wg + (size_t)r * C_CH) + half * (C_CH / 8);
        const float* mh = m + half * (C_CH / 2);
        float a0 = 0.f, a1 = 0.f;
#pragma unroll 8
        for (int i = 0; i < C_CH / 8; ++i) {      // 64 float4 = 256 floats
            float4 v = w4[i];
            const int c = i * 4;
            a0 += v.x * mh[c + 0] + v.y * mh[c + 1];
            a1 += v.z * mh[c + 2] + v.w * mh[c + 3];
        }
        part[tid] = a0 + a1;
    }
    __syncthreads();
    if (tid < R_CH) t[tid] = relu6f(part[tid] + part[tid + R_CH]);
    __syncthreads();

    // y[c] = relu6(BN(dot(wf[c,:], t))) for the block's PPB channels.
    if (tid < PPB) {
        const int c = c0 + tid;
        const float4* w4 = (const float4*)(wf + (size_t)c * R_CH);
        float a0 = 0.f, a1 = 0.f;
#pragma unroll
        for (int i = 0; i < R_CH / 4; ++i) {
            float4 v = w4[i];
            const int r = i * 4;
            a0 += v.x * t[r + 0] + v.y * t[r + 1];
            a1 += v.z * t[r + 2] + v.w * t[r + 3];
        }
        const float s = a0 + a1;
        const float inv_std = 1.0f / sqrtf(var[c] + 1e-5f);
        ys[tid] = relu6f((s - mu[c]) * inv_std * gamma[c] + beta[c]);
    }
    __syncthreads();

    // Stream: out = x + y[plane]; nt load + nt store.
#pragma unroll
    for (int p = 0; p < PPB; ++p) {
        const float a = ys[p];
        const floatx4* px = x + (size_t)(plane0 + p) * HW4;
        floatx4* po = out + (size_t)(plane0 + p) * HW4;
#pragma unroll
        for (int it = 0; it < HW4 / TPB; ++it) {
            const int i = tid + it * TPB;
            floatx4 v = __builtin_nontemporal_load(px + i);
            v += a;
            __builtin_nontemporal_store(v, po + i);
        }
    }
}

extern "C" void kernel_launch(void* const* d_in, const int* in_sizes, int n_in,
                              void* d_out, int out_size, void* d_ws, size_t ws_size,
                              hipStream_t stream) {
    const float4* x4    = (const float4*)d_in[0];
    const floatx4* xn   = (const floatx4*)d_in[0];
    const float* wg     = (const float*)d_in[1];
    const float* wf     = (const float*)d_in[2];
    const float* gamma  = (const float*)d_in[3];
    const float* beta   = (const float*)d_in[4];
    const float* mu     = (const float*)d_in[5];
    const float* var    = (const float*)d_in[6];

    float* meanv  = (float*)d_ws;      // NPLANE floats
    floatx4* out  = (floatx4*)d_out;

    // Software pipeline over 4 chunks of 2 batches (67 MB) each:
    //   mean(p0) mean(p1) add(p0) mean(p2) add(p1) mean(p3) add(p2) add(p3)
    // Launch boundaries impose the temporal order that makes the add pass's
    // x re-read hit the Infinity Cache lines the mean pass just allocated.
    mean_kernel<<<MEAN_BLOCKS, TPB, 0, stream>>>(x4, meanv, 0 * CHUNK_PLANES);
    mean_kernel<<<MEAN_BLOCKS, TPB, 0, stream>>>(x4, meanv, 1 * CHUNK_PLANES);
    add_kernel<<<ADD_BLOCKS, TPB, 0, stream>>>(xn, meanv, wg, wf, gamma, beta,
                                               mu, var, out, 0 * CHUNK_PLANES);
    mean_kernel<<<MEAN_BLOCKS, TPB, 0, stream>>>(x4, meanv, 2 * CHUNK_PLANES);
    add_kernel<<<ADD_BLOCKS, TPB, 0, stream>>>(xn, meanv, wg, wf, gamma, beta,
                                               mu, var, out, 1 * CHUNK_PLANES);
    mean_kernel<<<MEAN_BLOCKS, TPB, 0, stream>>>(x4, meanv, 3 * CHUNK_PLANES);
    add_kernel<<<ADD_BLOCKS, TPB, 0, stream>>>(xn, meanv, wg, wf, gamma, beta,
                                               mu, var, out, 2 * CHUNK_PLANES);
    add_kernel<<<ADD_BLOCKS, TPB, 0, stream>>>(xn, meanv, wg, wf, gamma, beta,
                                               mu, var, out, 3 * CHUNK_PLANES);
}